// Round 1
// baseline (858.149 us; speedup 1.0000x reference)
//
#include <hip/hip_runtime.h>
#include <stdint.h>

#define COLS 16384
#define TPB  256
#define EPT  64            // elements per thread (COLS / TPB)
#define NC   16            // histogram copies (bank-conflict mitigation)
#define CAP  (256 * NC)    // tie-index buffer capacity (reuses hist LDS)

// Order-preserving float->uint key: larger float => larger key.
__device__ __forceinline__ uint32_t f2key(float f) {
    uint32_t u = __float_as_uint(f);
    return u ^ (uint32_t)(((int32_t)u >> 31) | 0x80000000u);
}

__global__ void __launch_bounds__(TPB, 2)
topk_relu_kernel(const float* __restrict__ x, float* __restrict__ out) {
    __shared__ uint32_t hist[256 * NC];   // also reused as tie-index list
    __shared__ uint32_t bins[256];
    __shared__ uint32_t bcast[4];

    const int row = blockIdx.x;
    const int tid = threadIdx.x;
    const float4* xin  = (const float4*)(x   + (size_t)row * COLS);
    float4*       xout = (float4*)      (out + (size_t)row * COLS);

    // ---- load row, convert to sortable keys (floats not kept) ----
    uint32_t keys[EPT];
    #pragma unroll
    for (int j = 0; j < 16; ++j) {
        float4 v = xin[j * TPB + tid];
        keys[4*j+0] = f2key(v.x);
        keys[4*j+1] = f2key(v.y);
        keys[4*j+2] = f2key(v.z);
        keys[4*j+3] = f2key(v.w);
    }

    // ---- radix-256 select: find 32nd-largest key ----
    uint32_t prefix = 0, prefmask = 0;
    uint32_t k = 32;          // how many still to take at current level
    uint32_t count_eq = 0;    // population of chosen bin at current level
    const int copy = tid & (NC - 1);

    #pragma unroll 1
    for (int pass = 0; pass < 4; ++pass) {
        const int shift = 24 - 8 * pass;

        #pragma unroll
        for (int i = 0; i < NC; ++i) hist[tid + i * TPB] = 0;
        __syncthreads();

        #pragma unroll
        for (int e = 0; e < EPT; ++e) {
            uint32_t kk = keys[e];
            if ((kk & prefmask) == prefix)
                atomicAdd(&hist[(((kk >> shift) & 255u) * NC) + copy], 1u);
        }
        __syncthreads();

        uint32_t s = 0;
        #pragma unroll
        for (int c = 0; c < NC; ++c) s += hist[tid * NC + c];
        bins[tid] = s;
        __syncthreads();

        // wave 0: suffix scan from top bin, find crossing bin
        if (tid < 64) {
            uint32_t b0 = bins[255 - 4*tid];
            uint32_t b1 = bins[254 - 4*tid];
            uint32_t b2 = bins[253 - 4*tid];
            uint32_t b3 = bins[252 - 4*tid];
            uint32_t loc = b0 + b1 + b2 + b3;
            uint32_t v = loc;
            #pragma unroll
            for (int off = 1; off < 64; off <<= 1) {
                uint32_t t = __shfl_up(v, off, 64);
                if (tid >= off) v += t;
            }
            uint32_t pre = v - loc;   // count in bins strictly above my chunk
            if (pre < k && pre + loc >= k) {
                uint32_t bin, above, cnt;
                uint32_t c0 = pre + b0, c1 = c0 + b1, c2 = c1 + b2;
                if (c0 >= k)      { bin = 255 - 4*tid; above = pre; cnt = b0; }
                else if (c1 >= k) { bin = 254 - 4*tid; above = c0;  cnt = b1; }
                else if (c2 >= k) { bin = 253 - 4*tid; above = c1;  cnt = b2; }
                else              { bin = 252 - 4*tid; above = c2;  cnt = b3; }
                bcast[0] = bin;
                bcast[1] = k - above;  // new k (elements to take inside bin)
                bcast[2] = cnt;        // bin population
            }
        }
        __syncthreads();
        uint32_t bin = bcast[0];
        k        = bcast[1];
        count_eq = bcast[2];
        prefix  |= bin << shift;
        prefmask |= 0xFFu << shift;
        if (k == count_eq) break;   // uniform: all remaining matches are kept
    }

    const uint32_t P = prefix, M = prefmask;

    // ---- rare exact-tie path: count_eq != k only possible after full 4
    // passes (prefmask full). Only matters if tied value is positive. ----
    bool rare = (count_eq != k) && (P > 0x80000000u);
    uint32_t nlist = 0;
    if (rare) {
        if (tid == 0) bcast[3] = 0;
        __syncthreads();
        #pragma unroll
        for (int e = 0; e < EPT; ++e) {
            if (keys[e] == P) {
                uint32_t p = atomicAdd(&bcast[3], 1u);
                uint32_t idx = (uint32_t)((((e >> 2) * TPB + tid) << 2) + (e & 3));
                if (p < CAP) hist[p] = idx;
            }
        }
        __syncthreads();
        uint32_t total = bcast[3];
        nlist = total < (uint32_t)CAP ? total : (uint32_t)CAP;
    }

    // ---- output: relu(value) at kept positions, 0 elsewhere ----
    #pragma unroll
    for (int j = 0; j < 16; ++j) {
        float4 o;
        float* op = (float*)&o;
        #pragma unroll
        for (int c = 0; c < 4; ++c) {
            uint32_t kk = keys[4*j + c];
            uint32_t kkm = kk & M;
            bool keep;
            if (kkm > P) {
                keep = true;
            } else if (kkm == P) {
                if (!rare) {
                    keep = true;
                } else {
                    // lowest-index-wins among exact ties (jax top_k semantics)
                    uint32_t idx = (uint32_t)(((j * TPB + tid) << 2) + c);
                    uint32_t rank = 0;
                    for (uint32_t p = 0; p < nlist; ++p) rank += (hist[p] < idx);
                    keep = (rank < k);
                }
            } else {
                keep = false;
            }
            op[c] = (keep && kk > 0x80000000u)
                        ? __uint_as_float(kk ^ 0x80000000u) : 0.0f;
        }
        xout[j * TPB + tid] = o;
    }
}

extern "C" void kernel_launch(void* const* d_in, const int* in_sizes, int n_in,
                              void* d_out, int out_size, void* d_ws, size_t ws_size,
                              hipStream_t stream) {
    const float* x = (const float*)d_in[0];
    float* out = (float*)d_out;
    const int rows = in_sizes[0] / COLS;
    topk_relu_kernel<<<rows, TPB, 0, stream>>>(x, out);
}

// Round 2
// 841.888 us; speedup vs baseline: 1.0193x; 1.0193x over previous
//
#include <hip/hip_runtime.h>
#include <stdint.h>

#define COLS 16384
#define TPB  1024
#define EPT  16            // elements per thread (COLS / TPB)
#define NF4  4             // float4 loads per thread
#define NC   16            // histogram copies (bank-conflict mitigation)
#define CAP  (256 * NC)    // tie-index buffer capacity (reuses hist LDS)

// Order-preserving float->uint key: larger float => larger key.
__device__ __forceinline__ uint32_t f2key(float f) {
    uint32_t u = __float_as_uint(f);
    return u ^ (uint32_t)(((int32_t)u >> 31) | 0x80000000u);
}

__global__ void __launch_bounds__(TPB, 8)
topk_relu_kernel(const float* __restrict__ x, float* __restrict__ out) {
    __shared__ uint32_t hist[256 * NC];   // also reused as tie-index list
    __shared__ uint32_t bins[256];
    __shared__ uint32_t bcast[4];

    const int row = blockIdx.x;
    const int tid = threadIdx.x;
    const float4* xin  = (const float4*)(x   + (size_t)row * COLS);
    float4*       xout = (float4*)      (out + (size_t)row * COLS);

    // ---- load row, convert to sortable keys (floats not kept) ----
    uint32_t keys[EPT];
    #pragma unroll
    for (int j = 0; j < NF4; ++j) {
        float4 v = xin[j * TPB + tid];
        keys[4*j+0] = f2key(v.x);
        keys[4*j+1] = f2key(v.y);
        keys[4*j+2] = f2key(v.z);
        keys[4*j+3] = f2key(v.w);
    }

    // ---- radix-256 select: find 32nd-largest key ----
    uint32_t prefix = 0, prefmask = 0;
    uint32_t k = 32;          // how many still to take at current level
    uint32_t count_eq = 0;    // population of chosen bin at current level
    const int copy = tid & (NC - 1);

    #pragma unroll 1
    for (int pass = 0; pass < 4; ++pass) {
        const int shift = 24 - 8 * pass;

        #pragma unroll
        for (int i = tid; i < 256 * NC; i += TPB) hist[i] = 0;
        __syncthreads();

        #pragma unroll
        for (int e = 0; e < EPT; ++e) {
            uint32_t kk = keys[e];
            if ((kk & prefmask) == prefix)
                atomicAdd(&hist[(((kk >> shift) & 255u) * NC) + copy], 1u);
        }
        __syncthreads();

        if (tid < 256) {
            uint32_t s = 0;
            #pragma unroll
            for (int c = 0; c < NC; ++c) s += hist[tid * NC + c];
            bins[tid] = s;
        }
        __syncthreads();

        // wave 0: suffix scan from top bin, find crossing bin
        if (tid < 64) {
            uint32_t b0 = bins[255 - 4*tid];
            uint32_t b1 = bins[254 - 4*tid];
            uint32_t b2 = bins[253 - 4*tid];
            uint32_t b3 = bins[252 - 4*tid];
            uint32_t loc = b0 + b1 + b2 + b3;
            uint32_t v = loc;
            #pragma unroll
            for (int off = 1; off < 64; off <<= 1) {
                uint32_t t = __shfl_up(v, off, 64);
                if (tid >= off) v += t;
            }
            uint32_t pre = v - loc;   // count in bins strictly above my chunk
            if (pre < k && pre + loc >= k) {
                uint32_t bin, above, cnt;
                uint32_t c0 = pre + b0, c1 = c0 + b1, c2 = c1 + b2;
                if (c0 >= k)      { bin = 255 - 4*tid; above = pre; cnt = b0; }
                else if (c1 >= k) { bin = 254 - 4*tid; above = c0;  cnt = b1; }
                else if (c2 >= k) { bin = 253 - 4*tid; above = c1;  cnt = b2; }
                else              { bin = 252 - 4*tid; above = c2;  cnt = b3; }
                bcast[0] = bin;
                bcast[1] = k - above;  // new k (elements to take inside bin)
                bcast[2] = cnt;        // bin population
            }
        }
        __syncthreads();
        uint32_t bin = bcast[0];
        k        = bcast[1];
        count_eq = bcast[2];
        prefix  |= bin << shift;
        prefmask |= 0xFFu << shift;
        if (k == count_eq) break;   // uniform: all remaining matches are kept
    }

    const uint32_t P = prefix, M = prefmask;

    // ---- rare exact-tie path: count_eq != k only possible after full 4
    // passes (prefmask full). Only matters if tied value is positive. ----
    bool rare = (count_eq != k) && (P > 0x80000000u);
    uint32_t nlist = 0;
    if (rare) {
        if (tid == 0) bcast[3] = 0;
        __syncthreads();
        #pragma unroll
        for (int e = 0; e < EPT; ++e) {
            if (keys[e] == P) {
                uint32_t p = atomicAdd(&bcast[3], 1u);
                uint32_t idx = (uint32_t)((((e >> 2) * TPB + tid) << 2) + (e & 3));
                if (p < CAP) hist[p] = idx;
            }
        }
        __syncthreads();
        uint32_t total = bcast[3];
        nlist = total < (uint32_t)CAP ? total : (uint32_t)CAP;
    }

    // ---- output: relu(value) at kept positions, 0 elsewhere ----
    #pragma unroll
    for (int j = 0; j < NF4; ++j) {
        float4 o;
        float* op = (float*)&o;
        #pragma unroll
        for (int c = 0; c < 4; ++c) {
            uint32_t kk = keys[4*j + c];
            uint32_t kkm = kk & M;
            bool keep;
            if (kkm > P) {
                keep = true;
            } else if (kkm == P) {
                if (!rare) {
                    keep = true;
                } else {
                    // lowest-index-wins among exact ties (jax top_k semantics)
                    uint32_t idx = (uint32_t)(((j * TPB + tid) << 2) + c);
                    uint32_t rank = 0;
                    for (uint32_t p = 0; p < nlist; ++p) rank += (hist[p] < idx);
                    keep = (rank < k);
                }
            } else {
                keep = false;
            }
            op[c] = (keep && kk > 0x80000000u)
                        ? __uint_as_float(kk ^ 0x80000000u) : 0.0f;
        }
        xout[j * TPB + tid] = o;
    }
}

extern "C" void kernel_launch(void* const* d_in, const int* in_sizes, int n_in,
                              void* d_out, int out_size, void* d_ws, size_t ws_size,
                              hipStream_t stream) {
    const float* x = (const float*)d_in[0];
    float* out = (float*)d_out;
    const int rows = in_sizes[0] / COLS;
    topk_relu_kernel<<<rows, TPB, 0, stream>>>(x, out);
}